// Round 14
// baseline (441.664 us; speedup 1.0000x reference)
//
#include <hip/hip_runtime.h>
#include <stdint.h>

#define H 16
#define DK 64
#define QL 1024
#define KT 2048
#define DM 1024
#define BATCH 2

typedef __attribute__((ext_vector_type(4))) float f32x4;
typedef __attribute__((ext_vector_type(8))) short s16x8;

enum { EPI_K = 0, EPI_V = 1, EPI_QUV = 2, EPI_P = 3, EPI_OUT = 4 };

__device__ __forceinline__ unsigned short f2bf(float f) {
  union { float f; uint32_t u; } v; v.f = f;
  uint32_t u = v.u;
  u += 0x7fffu + ((u >> 16) & 1u);   // RNE
  return (unsigned short)(u >> 16);
}

#define MFMA_BF16(A, B, C) __builtin_amdgcn_mfma_f32_16x16x32_bf16((A), (B), (C), 0, 0, 0)

__device__ __forceinline__ void gld_lds16(const void* g, void* l) {
  __builtin_amdgcn_global_load_lds(
      (const __attribute__((address_space(1))) void*)g,
      (__attribute__((address_space(3))) void*)l, 16, 0, 0);
}

// pack 8 f32 (two f32x4, ascending k) -> s16x8 bf16 fragment (RNE)
__device__ __forceinline__ s16x8 cvt8(const f32x4& a, const f32x4& b) {
  union { uint32_t u[4]; s16x8 v; } r;
  asm("v_cvt_pk_bf16_f32 %0, %1, %2" : "=v"(r.u[0]) : "v"(a[0]), "v"(a[1]));
  asm("v_cvt_pk_bf16_f32 %0, %1, %2" : "=v"(r.u[1]) : "v"(a[2]), "v"(a[3]));
  asm("v_cvt_pk_bf16_f32 %0, %1, %2" : "=v"(r.u[2]) : "v"(b[0]), "v"(b[1]));
  asm("v_cvt_pk_bf16_f32 %0, %1, %2" : "=v"(r.u[3]) : "v"(b[2]), "v"(b[3]));
  return r.v;
}

// ---------------- prep kernels ----------------

__global__ __launch_bounds__(256) void cast_kv_kernel(
    const float* __restrict__ mem, const float* __restrict__ keyx,
    unsigned short* __restrict__ kv) {
  size_t i4 = (size_t)blockIdx.x * blockDim.x + threadIdx.x;
  if (i4 >= (size_t)BATCH * KT * DM / 4) return;
  size_t e = i4 * 4;
  int b = (int)(e >> 21);
  int rem = (int)(e & ((1u << 21) - 1));
  int j = rem >> 10;
  int d = rem & 1023;
  const float* src = (j < 1024)
      ? (mem + ((size_t)b << 20) + ((size_t)j << 10) + d)
      : (keyx + ((size_t)b << 20) + ((size_t)(j - 1024) << 10) + d);
  float4 v = *(const float4*)src;
  ushort4 o;
  o.x = f2bf(v.x); o.y = f2bf(v.y); o.z = f2bf(v.z); o.w = f2bf(v.w);
  *(ushort4*)(kv + e) = o;
}

__global__ __launch_bounds__(256) void cast4_kernel(
    const float* __restrict__ src, unsigned short* __restrict__ dst, int n4) {
  int i4 = blockIdx.x * blockDim.x + threadIdx.x;
  if (i4 >= n4) return;
  float4 v = *(const float4*)(src + (size_t)i4 * 4);
  ushort4 o;
  o.x = f2bf(v.x); o.y = f2bf(v.y); o.z = f2bf(v.z); o.w = f2bf(v.w);
  *(ushort4*)(dst + (size_t)i4 * 4) = o;
}

__global__ __launch_bounds__(256) void transpose_cast_kernel(
    const float* __restrict__ w0, const float* __restrict__ w1,
    const float* __restrict__ w2, const float* __restrict__ w3,
    const float* __restrict__ w4,
    unsigned short* __restrict__ o0, unsigned short* __restrict__ o1,
    unsigned short* __restrict__ o2, unsigned short* __restrict__ o3,
    unsigned short* __restrict__ o4) {
  __shared__ float tile[32][33];
  const float* src; unsigned short* dst;
  switch (blockIdx.z) {
    case 0: src = w0; dst = o0; break;
    case 1: src = w1; dst = o1; break;
    case 2: src = w2; dst = o2; break;
    case 3: src = w3; dst = o3; break;
    default: src = w4; dst = o4; break;
  }
  int bx = blockIdx.x * 32, by = blockIdx.y * 32;
  int tx = threadIdx.x;   // 0..31
  int ty = threadIdx.y;   // 0..7
#pragma unroll
  for (int r = 0; r < 4; ++r)
    tile[ty + r * 8][tx] = src[(size_t)(by + ty + r * 8) * DM + bx + tx];
  __syncthreads();
#pragma unroll
  for (int r = 0; r < 4; ++r)
    dst[(size_t)(bx + ty + r * 8) * DM + by + tx] = f2bf(tile[tx][ty + r * 8]);
}

__global__ __launch_bounds__(256) void pack_mask_kernel(
    const int* __restrict__ mask, unsigned long long* __restrict__ bits) {
  int t = blockIdx.x * blockDim.x + threadIdx.x;
  int wid = t >> 6, lane = t & 63;
  int v = mask[(size_t)wid * 64 + lane];
  unsigned long long bb = __ballot(v != 0);
  if (lane == 0) bits[wid] = bb;
}

// ---------------- GEMM body: C[m][n] = sum_k A[m][k] * B[n][k], K=1024 ----------------

__device__ __forceinline__ void gemm_body(
    const unsigned short* __restrict__ A, const unsigned short* __restrict__ B,
    int mode,
    unsigned short* __restrict__ out0, unsigned short* __restrict__ out1,
    float* __restrict__ outf,
    const float* __restrict__ uvec, const float* __restrict__ vvec,
    int bx, int by) {
  __shared__ __align__(16) unsigned short lds[128 * 64 * 2];  // A tile + B tile
  char* As = (char*)lds;
  char* Bs = (char*)lds + 128 * 64 * 2;

  const int tid = threadIdx.x;
  const int w = tid >> 6, lane = tid & 63;
  const int g = lane >> 4, l15 = lane & 15;
  const int m0 = by * 128, n0 = bx * 128;
  const int wm = w >> 1, wn = w & 1;
  const int K = 1024;

  f32x4 zf = {0.f, 0.f, 0.f, 0.f};
  f32x4 acc[4][4];
#pragma unroll
  for (int a = 0; a < 4; ++a)
#pragma unroll
    for (int c = 0; c < 4; ++c) acc[a][c] = zf;

  for (int kt = 0; kt < K; kt += 64) {
#pragma unroll
    for (int q = 0; q < 4; ++q) {
      int o = (w * 4 + q) * 1024 + lane * 16;   // byte offset in tile
      int row = o >> 7;
      int slot = (o & 127) >> 4;
      int ks = slot ^ (row & 7);                // pre-swizzled global source
      gld_lds16(A + (size_t)(m0 + row) * K + kt + ks * 8, As + o);
      gld_lds16(B + (size_t)(n0 + row) * K + kt + ks * 8, Bs + o);
    }
    asm volatile("s_waitcnt vmcnt(0)" ::: "memory");
    __syncthreads();
#pragma unroll
    for (int kk = 0; kk < 2; ++kk) {
      s16x8 af[4], bfr[4];
#pragma unroll
      for (int mf = 0; mf < 4; ++mf) {
        int row = wm * 64 + mf * 16 + l15;
        af[mf] = *(const s16x8*)(As + row * 128 + ((kk * 64 + g * 16) ^ ((row & 7) << 4)));
      }
#pragma unroll
      for (int nf = 0; nf < 4; ++nf) {
        int row = wn * 64 + nf * 16 + l15;
        bfr[nf] = *(const s16x8*)(Bs + row * 128 + ((kk * 64 + g * 16) ^ ((row & 7) << 4)));
      }
#pragma unroll
      for (int mf = 0; mf < 4; ++mf)
#pragma unroll
        for (int nf = 0; nf < 4; ++nf)
          acc[mf][nf] = MFMA_BF16(af[mf], bfr[nf], acc[mf][nf]);
    }
    __syncthreads();
  }

#pragma unroll
  for (int mf = 0; mf < 4; ++mf) {
#pragma unroll
    for (int nf = 0; nf < 4; ++nf) {
#pragma unroll
      for (int i = 0; i < 4; ++i) {
        int m = m0 + wm * 64 + mf * 16 + g * 4 + i;
        int n = n0 + wn * 64 + nf * 16 + l15;
        float val = acc[mf][nf][i];
        if (mode == EPI_K) {
          int b = m >> 11, j = m & 2047, hh = n >> 6, d = n & 63;
          out0[(((size_t)(b * H + hh) * KT + j) << 6) + d] = f2bf(val);
        } else if (mode == EPI_V) {  // swapped roles: m=(h,d), n=(b,j)
          int hh = m >> 6, d = m & 63, b = n >> 11, j = n & 2047;
          out0[((size_t)(b * H + hh) * 64 + d) * KT + j] = f2bf(val);
        } else if (mode == EPI_QUV) {
          int b = m >> 10, i2 = m & 1023, hh = n >> 6, d = n & 63;
          size_t idx = ((size_t)(b * H + hh) * QL + i2) * 64 + d;
          out0[idx] = f2bf(val + uvec[n]);
          out1[idx] = f2bf(val + vvec[n]);
        } else if (mode == EPI_P) {
          int hh = n >> 6, d = n & 63;
          out0[(((size_t)hh * KT + m) << 6) + d] = f2bf(val);
        } else {  // EPI_OUT: fp32
          outf[(size_t)m * DM + n] = val;
        }
      }
    }
  }
}

// fused projections: 768 blocks = 256 (K) + 256 (V) + 128 (QUV) + 128 (P)
__global__ __launch_bounds__(256) void gemm_fused_kernel(
    const unsigned short* __restrict__ kv, const unsigned short* __restrict__ q_b,
    const unsigned short* __restrict__ pos_b,
    const unsigned short* __restrict__ wk, const unsigned short* __restrict__ wv,
    const unsigned short* __restrict__ wq, const unsigned short* __restrict__ wp,
    unsigned short* __restrict__ Kp, unsigned short* __restrict__ Vt,
    unsigned short* __restrict__ Qu, unsigned short* __restrict__ Qv,
    unsigned short* __restrict__ Pp,
    const float* __restrict__ u, const float* __restrict__ v) {
  int bid = blockIdx.x;
  const unsigned short *A, *B;
  unsigned short *o0, *o1 = nullptr;
  int mode, bx, by;
  if (bid < 256)      { A = kv;    B = wk; mode = EPI_K;   o0 = Kp; bx = bid & 7;  by = bid >> 3; }
  else if (bid < 512) { bid -= 256; A = wv; B = kv; mode = EPI_V;   o0 = Vt; bx = bid & 31; by = bid >> 5; }
  else if (bid < 640) { bid -= 512; A = q_b; B = wq; mode = EPI_QUV; o0 = Qu; o1 = Qv; bx = bid & 7; by = bid >> 3; }
  else                { bid -= 640; A = pos_b; B = wp; mode = EPI_P; o0 = Pp; bx = bid & 7; by = bid >> 3; }
  gemm_body(A, B, mode, o0, o1, nullptr, u, v, bx, by);
}

__global__ __launch_bounds__(256) void gemm_out_kernel(
    const unsigned short* __restrict__ A, const unsigned short* __restrict__ B,
    float* __restrict__ outf) {
  gemm_body(A, B, EPI_OUT, nullptr, nullptr, outf, nullptr, nullptr, blockIdx.x, blockIdx.y);
}

// ---------------- fused relative attention ----------------
// Pass 1 computes e ONCE (register-resident BD via per-wave aligned chunks +
// 16-lane shuffle gather), stores w = exp(e) (fp32, unnormalized) to aw and
// row-sum partials to lsum. No running max: |e| <= ~4 here, exp(e) <= ~55,
// masked entries give exp(-1e30) == 0 exactly. exp(e)/sum == exp(e-m)*rl.
// Pass 2 (attn_pv) is a thin streaming kernel: normalize aw in place, build
// bf16 A-fragments in-register, PV MFMA, atomic-accumulate Oacc (normalized).

__device__ __forceinline__ void bd_chunk(
    f32x4 (&out)[4], const unsigned short* __restrict__ Pp_b,
    const s16x8* qv, const s16x8* qvp, int tbase, int g, int l15) {
  const s16x8 zv = {0, 0, 0, 0, 0, 0, 0, 0};
  const f32x4 zf = {0.f, 0.f, 0.f, 0.f};
#pragma unroll
  for (int nf = 0; nf < 4; ++nf) {
    const int F0 = tbase + nf * 16;
    const bool wrap = (F0 >= KT);
    const int prow = (wrap ? F0 - (KT + 1) : F0) + l15;   // -1 only at t==2048 lane
    const s16x8* psrc = (const s16x8*)(Pp_b + (size_t)(prow < 0 ? 0 : prow) * 64 + g * 8);
    f32x4 c = zf;
#pragma unroll
    for (int kk = 0; kk < 2; ++kk) {
      s16x8 pb = psrc[kk * 4];
      if (prow < 0) pb = zv;
      c = MFMA_BF16(wrap ? qvp[kk] : qv[kk], pb, c);
    }
    out[nf] = c;
  }
}

__device__ __forceinline__ void bd_gather(
    float (&bd)[4][4], const f32x4 (&cur)[4], const f32x4& nxt0,
    const int (&slan)[4], const bool (&crr)[4]) {
#pragma unroll
  for (int i = 0; i < 4; ++i) {
    float s0 = __shfl(cur[0][i], slan[i]);
    float s1 = __shfl(cur[1][i], slan[i]);
    float s2 = __shfl(cur[2][i], slan[i]);
    float s3 = __shfl(cur[3][i], slan[i]);
    float s4 = __shfl(nxt0[i], slan[i]);
    bd[0][i] = crr[i] ? s1 : s0;
    bd[1][i] = crr[i] ? s2 : s1;
    bd[2][i] = crr[i] ? s3 : s2;
    bd[3][i] = crr[i] ? s4 : s3;
  }
}

__device__ __forceinline__ void load_k(
    s16x8 (&kb)[2][4], const unsigned short* __restrict__ Kp_b,
    int j0, int g, int l15) {
#pragma unroll
  for (int nf = 0; nf < 4; ++nf) {
    const s16x8* p = (const s16x8*)(Kp_b + (size_t)(j0 + nf * 16 + l15) * 64 + g * 8);
    kb[0][nf] = p[0];
    kb[1][nf] = p[4];
  }
}

__device__ __forceinline__ void load_v(
    s16x8 (&vb)[2][4], const unsigned short* __restrict__ Vt_b,
    int j0, int g, int l15) {
#pragma unroll
  for (int df = 0; df < 4; ++df) {
    const unsigned short* p = Vt_b + (size_t)(df * 16 + l15) * KT + j0 + g * 8;
    vb[0][df] = *(const s16x8*)(p);
    vb[1][df] = *(const s16x8*)(p + 32);
  }
}

__device__ __forceinline__ void qk_acc(
    f32x4 (&acc)[4], const s16x8* qu, const s16x8 (&kb)[2][4]) {
#pragma unroll
  for (int kk = 0; kk < 2; ++kk)
#pragma unroll
    for (int nf = 0; nf < 4; ++nf)
      acc[nf] = MFMA_BF16(qu[kk], kb[kk][nf], acc[nf]);
}

__device__ __forceinline__ void make_e(
    float (&e)[4][4], const f32x4 (&acc)[4], const float (&bd)[4][4],
    const unsigned long long* __restrict__ mb_b,
    int r0, int s, int g, int l15) {
#pragma unroll
  for (int i = 0; i < 4; ++i) {
    unsigned long long mw = mb_b[(size_t)(r0 + g * 4 + i) * 32 + s];
#pragma unroll
    for (int nf = 0; nf < 4; ++nf) {
      float ev = (acc[nf][i] + bd[nf][i]) * 0.125f;
      e[nf][i] = ((mw >> (nf * 16 + l15)) & 1ull) ? ev : -1e30f;
    }
  }
}

// block decode with XCD swizzle: 4096 blocks, logical = bh*128 + jq*16 + rblk
#define ATTN_DECODE()                                                  \
  const int w = threadIdx.x >> 6, lane = threadIdx.x & 63;             \
  const int g = lane >> 4, l15 = lane & 15;                            \
  const int logical = ((blockIdx.x & 7) << 9) | (blockIdx.x >> 3);     \
  const int rblk = logical & 15, jq = (logical >> 4) & 7, bh = logical >> 7; \
  const int b = bh >> 4, h = bh & 15;                                  \
  const int r0 = rblk * 64 + w * 16;                                   \
  (void)b; (void)h; (void)lane;

#define ATTN_PROLOGUE()                                                \
  s16x8 zv = {0, 0, 0, 0, 0, 0, 0, 0};                                 \
  s16x8 qu[2], qv[2], qvp[2];                                          \
  {                                                                    \
    int r = r0 + l15;                                                  \
    const s16x8* pq = (const s16x8*)(Qu_b + (size_t)r * 64 + g * 8);   \
    const s16x8* pv = (const s16x8*)(Qv_b + (size_t)r * 64 + g * 8);   \
    qu[0] = pq[0]; qu[1] = pq[4];                                      \
    qv[0] = pv[0]; qv[1] = pv[4];                                      \
    int rp = r0 + 1 + l15;                                             \
    if (rp < QL) {                                                     \
      const s16x8* pp = (const s16x8*)(Qv_b + (size_t)rp * 64 + g * 8);\
      qvp[0] = pp[0]; qvp[1] = pp[4];                                  \
    } else { qvp[0] = zv; qvp[1] = zv; }                               \
  }                                                                    \
  int slan[4]; bool crr[4];                                            \
  _Pragma("unroll")                                                    \
  for (int i = 0; i < 4; ++i) {                                        \
    int g4i = g * 4 + i;                                               \
    slan[i] = (lane & 48) | ((l15 + 15 - g4i) & 15);                   \
    crr[i] = (l15 >= g4i + 1);                                         \
  }                                                                    \
  const int sq0 = jq * 4;                                              \
  const int tb0 = sq0 * 64 + 1008 - r0;

// P1: e once; w=exp(e) -> aw (unnormalized); row-sum partials -> lsum.
// 4096 blocks, 256 threads, no LDS.
__global__ __launch_bounds__(256) void attn_p1(
    const unsigned short* __restrict__ Qu, const unsigned short* __restrict__ Qv,
    const unsigned short* __restrict__ Kp, const unsigned short* __restrict__ Pp,
    const unsigned long long* __restrict__ mbits,
    float* __restrict__ aw, float* __restrict__ lsum, float* __restrict__ Oacc) {
  ATTN_DECODE();

  if (jq == 0) {  // zero the O accumulator region for these rows (16KB/block)
    float4 z4 = {0.f, 0.f, 0.f, 0.f};
    float* dst = Oacc + ((size_t)bh * QL + rblk * 64) * 64 + threadIdx.x * 16;
#pragma unroll
    for (int q = 0; q < 4; ++q) ((float4*)dst)[q] = z4;
  }

  const unsigned short* Qu_b = Qu + (size_t)bh * QL * 64;
  const unsigned short* Qv_b = Qv + (size_t)bh * QL * 64;
  const unsigned short* Kp_b = Kp + (size_t)bh * KT * 64;
  const unsigned short* Pp_b = Pp + (size_t)h * KT * 64;
  float* aw_b = aw + (size_t)bh * QL * KT;
  const unsigned long long* mb_b = mbits + (size_t)b * QL * 32;

  ATTN_PROLOGUE();

  float l_l[4] = {0.f, 0.f, 0.f, 0.f};

  f32x4 cur[4], nxt[4];
  bd_chunk(cur, Pp_b, qv, qvp, tb0, g, l15);
  s16x8 kb[2][4];
  load_k(kb, Kp_b, sq0 * 64, g, l15);

#pragma unroll
  for (int ss = 0; ss < 4; ++ss) {
    const int s = sq0 + ss;
    const int j0 = s * 64;
    bd_chunk(nxt, Pp_b, qv, qvp, tb0 + (ss + 1) * 64, g, l15);
    f32x4 acc[4];
#pragma unroll
    for (int nf = 0; nf < 4; ++nf) acc[nf] = f32x4{0.f, 0.f, 0.f, 0.f};
    qk_acc(acc, qu, kb);
    if (ss < 3) load_k(kb, Kp_b, (s + 1) * 64, g, l15);
    float bd[4][4];
    bd_gather(bd, cur, nxt[0], slan, crr);
    float e[4][4];
    make_e(e, acc, bd, mb_b, r0, s, g, l15);
#pragma unroll
    for (int nf = 0; nf < 4; ++nf)
#pragma unroll
      for (int i = 0; i < 4; ++i) {
        float p = __expf(e[nf][i]);   // masked -> exactly 0
        aw_b[(size_t)(r0 + g * 4 + i) * KT + j0 + nf * 16 + l15] = p;
        l_l[i] += p;
      }
#pragma unroll
    for (int nf = 0; nf < 4; ++nf) cur[nf] = nxt[nf];
  }

  // per-row l partial: 16-lane reduce, lane l15==0 writes rows g*4+i
#pragma unroll
  for (int i = 0; i < 4; ++i) {
    float sL = l_l[i];
#pragma unroll
    for (int d = 1; d < 16; d <<= 1) sL += __shfl_xor(sL, d);
    if (l15 == 0)
      lsum[((size_t)bh * QL + r0 + g * 4 + i) * 8 + jq] = sL;
  }
}

// rl[row] = 1 / sum(lsum[row][0..8))   (32768 rows)
__global__ __launch_bounds__(256) void rsum_kernel(
    const float* __restrict__ lsum, float* __restrict__ rl) {
  int r = blockIdx.x * 256 + threadIdx.x;
  const f32x4* p = (const f32x4*)(lsum + (size_t)r * 8);
  f32x4 a = p[0], c = p[1];
  rl[r] = 1.f / (a[0] + a[1] + a[2] + a[3] + c[0] + c[1] + c[2] + c[3]);
}

// PV pass: normalize aw in place, PV MFMA from in-register bf16 fragments,
// atomic-accumulate normalized O. Pure streaming, no LDS.
// Grid 2048 blocks (bh x jq x rblk), 8 steps each: 8 blocks/CU (32 waves/CU)
// for latency hiding; 8.4M atomics (half of the 4096-block variant).
__global__ __launch_bounds__(256) void attn_pv(
    const unsigned short* __restrict__ Vt, const float* __restrict__ rl,
    float* __restrict__ aw, float* __restrict__ Oacc) {
  const int w = threadIdx.x >> 6, lane = threadIdx.x & 63;
  const int g = lane >> 4, l15 = lane & 15;
  const int logical = ((blockIdx.x & 7) << 8) | (blockIdx.x >> 3);  // 2048 blocks, XCD swizzle
  const int rblk = logical & 15, jq = (logical >> 4) & 3, bh = logical >> 6;
  const int r0 = rblk * 64 + w * 16;

  const unsigned short* Vt_b = Vt + (size_t)bh * 64 * KT;
  float* aw_b = aw + (size_t)bh * QL * KT;
  const float rs = rl[(size_t)bh * QL + r0 + l15];   // this lane's A-row scale

  f32x4 accO[4];
#pragma unroll
  for (int df = 0; df < 4; ++df) accO[df] = f32x4{0.f, 0.f, 0.f, 0.f};

#pragma unroll 4
  for (int s2 = 0; s2 < 8; ++s2) {
    const int j0 = (jq * 8 + s2) * 64;
    float* ar = aw_b + (size_t)(r0 + l15) * KT + j0 + g * 8;
    f32x4 w0 = *(const f32x4*)(ar);
    f32x4 w1 = *(const f32x4*)(ar + 4);
    f32x4 w2 = *(const f32x4*)(ar + 32);
    f32x4 w3 = *(const f32x4*)(ar + 36);
    w0 *= rs; w1 *= rs; w2 *= rs; w3 *= rs;
    *(f32x4*)(ar) = w0;
    *(f32x4*)(ar + 4) = w1;
    *(f32x4*)(ar + 32) = w2;
    *(f32x4*)(ar + 36) = w3;
    s16x8 pa0 = cvt8(w0, w1);   // A-frag: row=l15, k = g*8..+8 (kk=0)
    s16x8 pa1 = cvt8(w2, w3);   // kk=1
    s16x8 vb[2][4];
    load_v(vb, Vt_b, j0, g, l15);
#pragma unroll
    for (int df = 0; df < 4; ++df) {
      accO[df] = MFMA_BF16(pa0, vb[0][df], accO[df]);
      accO[df] = MFMA_BF16(pa1, vb[1][df], accO[df]);
    }
  }

#pragma unroll
  for (int df = 0; df < 4; ++df)
#pragma unroll
    for (int i = 0; i < 4; ++i)
      atomicAdd(&Oacc[((size_t)bh * QL + r0 + g * 4 + i) * 64 + df * 16 + l15], accO[df][i]);
}

// C: Oacc [bh][r][64] f32 -> cvb [b][r][h*64+d] bf16
__global__ __launch_bounds__(256) void cast_cv_kernel(
    const float* __restrict__ Oacc, unsigned short* __restrict__ cvb) {
  int t = blockIdx.x * blockDim.x + threadIdx.x;
  int d4 = t & 15, r = (t >> 4) & 1023, bh = t >> 14;
  int b = bh >> 4, h = bh & 15;
  float4 v = ((const float4*)Oacc)[t];
  ushort4 o;
  o.x = f2bf(v.x); o.y = f2bf(v.y); o.z = f2bf(v.z); o.w = f2bf(v.w);
  *(ushort4*)(cvb + (size_t)(b * QL + r) * DM + h * 64 + d4 * 4) = o;
}

// ---------------- launch ----------------

extern "C" void kernel_launch(void* const* d_in, const int* in_sizes, int n_in,
                              void* d_out, int out_size, void* d_ws, size_t ws_size,
                              hipStream_t stream) {
  const float* key_x  = (const float*)d_in[0];
  const float* query  = (const float*)d_in[1];
  const float* memory = (const float*)d_in[2];
  const float* pose   = (const float*)d_in[3];
  const int*   mask   = (const int*)d_in[4];
  const float* u      = (const float*)d_in[5];
  const float* v      = (const float*)d_in[6];
  const float* w_key  = (const float*)d_in[7];
  const float* w_val  = (const float*)d_in[8];
  const float* w_qry  = (const float*)d_in[9];
  const float* w_pos  = (const float*)d_in[10];
  const float* w_out  = (const float*)d_in[11];

  char* ws = (char*)d_ws;
  const size_t MB = 1024 * 1024;
  unsigned short* kv_b  = (unsigned short*)(ws + 0);        // [2][2048][1024] bf16 (8MB)
  unsigned short* q_b   = (unsigned short*)(ws + 8 * MB);   // (4MB)
  unsigned short* pos_b = (unsigned short*)(ws + 12 * MB);  // (4MB)
  unsigned short* wk_t  = (unsigned short*)(ws + 16 * MB);
  unsigned short* wv_t  = (unsigned short*)(ws + 18 * MB);
  unsigned short* wq_t  = (unsigned short*)(ws + 20 * MB);
  unsigned short* wp_t  = (unsigned short*)(ws + 22 * MB);
  unsigned short* wo_t  = (unsigned short*)(ws + 24 * MB);
  unsigned short* Kp    = (unsigned short*)(ws + 26 * MB);  // [2][16][2048][64] (8MB)
  unsigned short* Vt    = (unsigned short*)(ws + 34 * MB);  // [2][16][64][2048] (8MB)
  unsigned short* Qu    = (unsigned short*)(ws + 42 * MB);  // (4MB)
  unsigned short* Qv    = (unsigned short*)(ws + 46 * MB);  // (4MB)
  unsigned short* Pp    = (unsigned short*)(ws + 50 * MB);  // [16][2048][64] (4MB)
  unsigned short* cvb   = (unsigned short*)(ws + 54 * MB);  // (4MB)
  unsigned long long* mb = (unsigned long long*)(ws + 58 * MB);  // (0.5MB)
  // reuse dead regions (after gemm_fused, kv_b/q_b are dead):
  float* Oacc = (float*)(ws + 0);        // [2][16][1024][64] f32 (8MB) over kv_b
  float* lsum = (float*)(ws + 8 * MB);   // [32768][8] f32 (1MB) over q_b
  float* rl   = (float*)(ws + 9 * MB);   // [32768] f32 (128KB) over q_b

  float* out_cv = (float*)d_out;
  float* out_aw = (float*)d_out + (size_t)BATCH * QL * DM;

  cast_kv_kernel<<<4096, 256, 0, stream>>>(memory, key_x, kv_b);
  cast4_kernel<<<2048, 256, 0, stream>>>(query, q_b, BATCH * QL * DM / 4);
  cast4_kernel<<<2048, 256, 0, stream>>>(pose, pos_b, KT * DM / 4);
  transpose_cast_kernel<<<dim3(32, 32, 5), dim3(32, 8), 0, stream>>>(
      w_key, w_val, w_qry, w_pos, w_out, wk_t, wv_t, wq_t, wp_t, wo_t);
  pack_mask_kernel<<<16384, 256, 0, stream>>>(mask, mb);

  gemm_fused_kernel<<<768, 256, 0, stream>>>(kv_b, q_b, pos_b, wk_t, wv_t, wq_t, wp_t,
                                             Kp, Vt, Qu, Qv, Pp, u, v);

  attn_p1<<<4096, 256, 0, stream>>>(Qu, Qv, Kp, Pp, mb, out_aw, lsum, Oacc);
  rsum_kernel<<<128, 256, 0, stream>>>(lsum, rl);
  attn_pv<<<2048, 256, 0, stream>>>(Vt, rl, out_aw, Oacc);
  cast_cv_kernel<<<2048, 256, 0, stream>>>(Oacc, cvb);

  gemm_out_kernel<<<dim3(8, 16), 256, 0, stream>>>(cvb, wo_t, out_cv);
}

// Round 15
// 439.399 us; speedup vs baseline: 1.0052x; 1.0052x over previous
//
#include <hip/hip_runtime.h>
#include <stdint.h>

#define H 16
#define DK 64
#define QL 1024
#define KT 2048
#define DM 1024
#define BATCH 2

typedef __attribute__((ext_vector_type(4))) float f32x4;
typedef __attribute__((ext_vector_type(8))) short s16x8;

enum { EPI_K = 0, EPI_V = 1, EPI_QUV = 2, EPI_P = 3, EPI_OUT = 4 };

__device__ __forceinline__ unsigned short f2bf(float f) {
  union { float f; uint32_t u; } v; v.f = f;
  uint32_t u = v.u;
  u += 0x7fffu + ((u >> 16) & 1u);   // RNE
  return (unsigned short)(u >> 16);
}
__device__ __forceinline__ float bf2f(unsigned short s) {
  union { uint32_t u; float f; } v; v.u = ((uint32_t)s) << 16;
  return v.f;
}

#define MFMA_BF16(A, B, C) __builtin_amdgcn_mfma_f32_16x16x32_bf16((A), (B), (C), 0, 0, 0)

__device__ __forceinline__ void gld_lds16(const void* g, void* l) {
  __builtin_amdgcn_global_load_lds(
      (const __attribute__((address_space(1))) void*)g,
      (__attribute__((address_space(3))) void*)l, 16, 0, 0);
}

// pack 8 f32 (two f32x4, ascending k) -> s16x8 bf16 fragment (RNE)
__device__ __forceinline__ s16x8 cvt8(const f32x4& a, const f32x4& b) {
  union { uint32_t u[4]; s16x8 v; } r;
  asm("v_cvt_pk_bf16_f32 %0, %1, %2" : "=v"(r.u[0]) : "v"(a[0]), "v"(a[1]));
  asm("v_cvt_pk_bf16_f32 %0, %1, %2" : "=v"(r.u[1]) : "v"(a[2]), "v"(a[3]));
  asm("v_cvt_pk_bf16_f32 %0, %1, %2" : "=v"(r.u[2]) : "v"(b[0]), "v"(b[1]));
  asm("v_cvt_pk_bf16_f32 %0, %1, %2" : "=v"(r.u[3]) : "v"(b[2]), "v"(b[3]));
  return r.v;
}

// ---------------- prep kernels ----------------

__global__ __launch_bounds__(256) void cast_kv_kernel(
    const float* __restrict__ mem, const float* __restrict__ keyx,
    unsigned short* __restrict__ kv) {
  size_t i4 = (size_t)blockIdx.x * blockDim.x + threadIdx.x;
  if (i4 >= (size_t)BATCH * KT * DM / 4) return;
  size_t e = i4 * 4;
  int b = (int)(e >> 21);
  int rem = (int)(e & ((1u << 21) - 1));
  int j = rem >> 10;
  int d = rem & 1023;
  const float* src = (j < 1024)
      ? (mem + ((size_t)b << 20) + ((size_t)j << 10) + d)
      : (keyx + ((size_t)b << 20) + ((size_t)(j - 1024) << 10) + d);
  float4 v = *(const float4*)src;
  ushort4 o;
  o.x = f2bf(v.x); o.y = f2bf(v.y); o.z = f2bf(v.z); o.w = f2bf(v.w);
  *(ushort4*)(kv + e) = o;
}

__global__ __launch_bounds__(256) void cast4_kernel(
    const float* __restrict__ src, unsigned short* __restrict__ dst, int n4) {
  int i4 = blockIdx.x * blockDim.x + threadIdx.x;
  if (i4 >= n4) return;
  float4 v = *(const float4*)(src + (size_t)i4 * 4);
  ushort4 o;
  o.x = f2bf(v.x); o.y = f2bf(v.y); o.z = f2bf(v.z); o.w = f2bf(v.w);
  *(ushort4*)(dst + (size_t)i4 * 4) = o;
}

__global__ __launch_bounds__(256) void transpose_cast_kernel(
    const float* __restrict__ w0, const float* __restrict__ w1,
    const float* __restrict__ w2, const float* __restrict__ w3,
    const float* __restrict__ w4,
    unsigned short* __restrict__ o0, unsigned short* __restrict__ o1,
    unsigned short* __restrict__ o2, unsigned short* __restrict__ o3,
    unsigned short* __restrict__ o4) {
  __shared__ float tile[32][33];
  const float* src; unsigned short* dst;
  switch (blockIdx.z) {
    case 0: src = w0; dst = o0; break;
    case 1: src = w1; dst = o1; break;
    case 2: src = w2; dst = o2; break;
    case 3: src = w3; dst = o3; break;
    default: src = w4; dst = o4; break;
  }
  int bx = blockIdx.x * 32, by = blockIdx.y * 32;
  int tx = threadIdx.x;   // 0..31
  int ty = threadIdx.y;   // 0..7
#pragma unroll
  for (int r = 0; r < 4; ++r)
    tile[ty + r * 8][tx] = src[(size_t)(by + ty + r * 8) * DM + bx + tx];
  __syncthreads();
#pragma unroll
  for (int r = 0; r < 4; ++r)
    dst[(size_t)(bx + ty + r * 8) * DM + by + tx] = f2bf(tile[tx][ty + r * 8]);
}

__global__ __launch_bounds__(256) void pack_mask_kernel(
    const int* __restrict__ mask, unsigned long long* __restrict__ bits) {
  int t = blockIdx.x * blockDim.x + threadIdx.x;
  int wid = t >> 6, lane = t & 63;
  int v = mask[(size_t)wid * 64 + lane];
  unsigned long long bb = __ballot(v != 0);
  if (lane == 0) bits[wid] = bb;
}

// ---------------- GEMM body: C[m][n] = sum_k A[m][k] * B[n][k], K=1024 ----------------

__device__ __forceinline__ void gemm_body(
    const unsigned short* __restrict__ A, const unsigned short* __restrict__ B,
    int mode,
    unsigned short* __restrict__ out0, unsigned short* __restrict__ out1,
    float* __restrict__ outf,
    const float* __restrict__ uvec, const float* __restrict__ vvec,
    int bx, int by) {
  __shared__ __align__(16) unsigned short lds[128 * 64 * 2];  // A tile + B tile
  char* As = (char*)lds;
  char* Bs = (char*)lds + 128 * 64 * 2;

  const int tid = threadIdx.x;
  const int w = tid >> 6, lane = tid & 63;
  const int g = lane >> 4, l15 = lane & 15;
  const int m0 = by * 128, n0 = bx * 128;
  const int wm = w >> 1, wn = w & 1;
  const int K = 1024;

  f32x4 zf = {0.f, 0.f, 0.f, 0.f};
  f32x4 acc[4][4];
#pragma unroll
  for (int a = 0; a < 4; ++a)
#pragma unroll
    for (int c = 0; c < 4; ++c) acc[a][c] = zf;

  for (int kt = 0; kt < K; kt += 64) {
#pragma unroll
    for (int q = 0; q < 4; ++q) {
      int o = (w * 4 + q) * 1024 + lane * 16;   // byte offset in tile
      int row = o >> 7;
      int slot = (o & 127) >> 4;
      int ks = slot ^ (row & 7);                // pre-swizzled global source
      gld_lds16(A + (size_t)(m0 + row) * K + kt + ks * 8, As + o);
      gld_lds16(B + (size_t)(n0 + row) * K + kt + ks * 8, Bs + o);
    }
    asm volatile("s_waitcnt vmcnt(0)" ::: "memory");
    __syncthreads();
#pragma unroll
    for (int kk = 0; kk < 2; ++kk) {
      s16x8 af[4], bfr[4];
#pragma unroll
      for (int mf = 0; mf < 4; ++mf) {
        int row = wm * 64 + mf * 16 + l15;
        af[mf] = *(const s16x8*)(As + row * 128 + ((kk * 64 + g * 16) ^ ((row & 7) << 4)));
      }
#pragma unroll
      for (int nf = 0; nf < 4; ++nf) {
        int row = wn * 64 + nf * 16 + l15;
        bfr[nf] = *(const s16x8*)(Bs + row * 128 + ((kk * 64 + g * 16) ^ ((row & 7) << 4)));
      }
#pragma unroll
      for (int mf = 0; mf < 4; ++mf)
#pragma unroll
        for (int nf = 0; nf < 4; ++nf)
          acc[mf][nf] = MFMA_BF16(af[mf], bfr[nf], acc[mf][nf]);
    }
    __syncthreads();
  }

#pragma unroll
  for (int mf = 0; mf < 4; ++mf) {
#pragma unroll
    for (int nf = 0; nf < 4; ++nf) {
#pragma unroll
      for (int i = 0; i < 4; ++i) {
        int m = m0 + wm * 64 + mf * 16 + g * 4 + i;
        int n = n0 + wn * 64 + nf * 16 + l15;
        float val = acc[mf][nf][i];
        if (mode == EPI_K) {
          int b = m >> 11, j = m & 2047, hh = n >> 6, d = n & 63;
          out0[(((size_t)(b * H + hh) * KT + j) << 6) + d] = f2bf(val);
        } else if (mode == EPI_V) {  // swapped roles: m=(h,d), n=(b,j)
          int hh = m >> 6, d = m & 63, b = n >> 11, j = n & 2047;
          out0[((size_t)(b * H + hh) * 64 + d) * KT + j] = f2bf(val);
        } else if (mode == EPI_QUV) {
          int b = m >> 10, i2 = m & 1023, hh = n >> 6, d = n & 63;
          size_t idx = ((size_t)(b * H + hh) * QL + i2) * 64 + d;
          out0[idx] = f2bf(val + uvec[n]);
          out1[idx] = f2bf(val + vvec[n]);
        } else if (mode == EPI_P) {
          int hh = n >> 6, d = n & 63;
          out0[(((size_t)hh * KT + m) << 6) + d] = f2bf(val);
        } else {  // EPI_OUT: fp32
          outf[(size_t)m * DM + n] = val;
        }
      }
    }
  }
}

// fused projections: 768 blocks = 256 (K) + 256 (V) + 128 (QUV) + 128 (P)
__global__ __launch_bounds__(256) void gemm_fused_kernel(
    const unsigned short* __restrict__ kv, const unsigned short* __restrict__ q_b,
    const unsigned short* __restrict__ pos_b,
    const unsigned short* __restrict__ wk, const unsigned short* __restrict__ wv,
    const unsigned short* __restrict__ wq, const unsigned short* __restrict__ wp,
    unsigned short* __restrict__ Kp, unsigned short* __restrict__ Vt,
    unsigned short* __restrict__ Qu, unsigned short* __restrict__ Qv,
    unsigned short* __restrict__ Pp,
    const float* __restrict__ u, const float* __restrict__ v) {
  int bid = blockIdx.x;
  const unsigned short *A, *B;
  unsigned short *o0, *o1 = nullptr;
  int mode, bx, by;
  if (bid < 256)      { A = kv;    B = wk; mode = EPI_K;   o0 = Kp; bx = bid & 7;  by = bid >> 3; }
  else if (bid < 512) { bid -= 256; A = wv; B = kv; mode = EPI_V;   o0 = Vt; bx = bid & 31; by = bid >> 5; }
  else if (bid < 640) { bid -= 512; A = q_b; B = wq; mode = EPI_QUV; o0 = Qu; o1 = Qv; bx = bid & 7; by = bid >> 3; }
  else                { bid -= 640; A = pos_b; B = wp; mode = EPI_P; o0 = Pp; bx = bid & 7; by = bid >> 3; }
  gemm_body(A, B, mode, o0, o1, nullptr, u, v, bx, by);
}

__global__ __launch_bounds__(256) void gemm_out_kernel(
    const unsigned short* __restrict__ A, const unsigned short* __restrict__ B,
    float* __restrict__ outf) {
  gemm_body(A, B, EPI_OUT, nullptr, nullptr, outf, nullptr, nullptr, blockIdx.x, blockIdx.y);
}

// ---------------- fused relative attention ----------------
// Pass 1 computes e ONCE, stores w = exp(e) (unnormalized) either as fp32 to
// aw (fallback) or as bf16 to a 134MB scratch (big-ws path; stays ~L3-resident),
// plus row-sum partials. Pass 2 normalizes (w*rl) -> fp32 aw (written once,
// nontemporal in bf16 path), builds bf16 fragments of the NORMALIZED values
// (same math as the validated R13/R14 kernels), PV MFMA, atomic-accumulate.

__device__ __forceinline__ void bd_chunk(
    f32x4 (&out)[4], const unsigned short* __restrict__ Pp_b,
    const s16x8* qv, const s16x8* qvp, int tbase, int g, int l15) {
  const s16x8 zv = {0, 0, 0, 0, 0, 0, 0, 0};
  const f32x4 zf = {0.f, 0.f, 0.f, 0.f};
#pragma unroll
  for (int nf = 0; nf < 4; ++nf) {
    const int F0 = tbase + nf * 16;
    const bool wrap = (F0 >= KT);
    const int prow = (wrap ? F0 - (KT + 1) : F0) + l15;   // -1 only at t==2048 lane
    const s16x8* psrc = (const s16x8*)(Pp_b + (size_t)(prow < 0 ? 0 : prow) * 64 + g * 8);
    f32x4 c = zf;
#pragma unroll
    for (int kk = 0; kk < 2; ++kk) {
      s16x8 pb = psrc[kk * 4];
      if (prow < 0) pb = zv;
      c = MFMA_BF16(wrap ? qvp[kk] : qv[kk], pb, c);
    }
    out[nf] = c;
  }
}

__device__ __forceinline__ void bd_gather(
    float (&bd)[4][4], const f32x4 (&cur)[4], const f32x4& nxt0,
    const int (&slan)[4], const bool (&crr)[4]) {
#pragma unroll
  for (int i = 0; i < 4; ++i) {
    float s0 = __shfl(cur[0][i], slan[i]);
    float s1 = __shfl(cur[1][i], slan[i]);
    float s2 = __shfl(cur[2][i], slan[i]);
    float s3 = __shfl(cur[3][i], slan[i]);
    float s4 = __shfl(nxt0[i], slan[i]);
    bd[0][i] = crr[i] ? s1 : s0;
    bd[1][i] = crr[i] ? s2 : s1;
    bd[2][i] = crr[i] ? s3 : s2;
    bd[3][i] = crr[i] ? s4 : s3;
  }
}

__device__ __forceinline__ void load_k(
    s16x8 (&kb)[2][4], const unsigned short* __restrict__ Kp_b,
    int j0, int g, int l15) {
#pragma unroll
  for (int nf = 0; nf < 4; ++nf) {
    const s16x8* p = (const s16x8*)(Kp_b + (size_t)(j0 + nf * 16 + l15) * 64 + g * 8);
    kb[0][nf] = p[0];
    kb[1][nf] = p[4];
  }
}

__device__ __forceinline__ void load_v(
    s16x8 (&vb)[2][4], const unsigned short* __restrict__ Vt_b,
    int j0, int g, int l15) {
#pragma unroll
  for (int df = 0; df < 4; ++df) {
    const unsigned short* p = Vt_b + (size_t)(df * 16 + l15) * KT + j0 + g * 8;
    vb[0][df] = *(const s16x8*)(p);
    vb[1][df] = *(const s16x8*)(p + 32);
  }
}

__device__ __forceinline__ void qk_acc(
    f32x4 (&acc)[4], const s16x8* qu, const s16x8 (&kb)[2][4]) {
#pragma unroll
  for (int kk = 0; kk < 2; ++kk)
#pragma unroll
    for (int nf = 0; nf < 4; ++nf)
      acc[nf] = MFMA_BF16(qu[kk], kb[kk][nf], acc[nf]);
}

__device__ __forceinline__ void make_e(
    float (&e)[4][4], const f32x4 (&acc)[4], const float (&bd)[4][4],
    const unsigned long long* __restrict__ mb_b,
    int r0, int s, int g, int l15) {
#pragma unroll
  for (int i = 0; i < 4; ++i) {
    unsigned long long mw = mb_b[(size_t)(r0 + g * 4 + i) * 32 + s];
#pragma unroll
    for (int nf = 0; nf < 4; ++nf) {
      float ev = (acc[nf][i] + bd[nf][i]) * 0.125f;
      e[nf][i] = ((mw >> (nf * 16 + l15)) & 1ull) ? ev : -1e30f;
    }
  }
}

// block decode with XCD swizzle: 4096 blocks, logical = bh*128 + jq*16 + rblk
#define ATTN_DECODE()                                                  \
  const int w = threadIdx.x >> 6, lane = threadIdx.x & 63;             \
  const int g = lane >> 4, l15 = lane & 15;                            \
  const int logical = ((blockIdx.x & 7) << 9) | (blockIdx.x >> 3);     \
  const int rblk = logical & 15, jq = (logical >> 4) & 7, bh = logical >> 7; \
  const int b = bh >> 4, h = bh & 15;                                  \
  const int r0 = rblk * 64 + w * 16;                                   \
  (void)b; (void)h; (void)lane;

#define ATTN_PROLOGUE()                                                \
  s16x8 zv = {0, 0, 0, 0, 0, 0, 0, 0};                                 \
  s16x8 qu[2], qv[2], qvp[2];                                          \
  {                                                                    \
    int r = r0 + l15;                                                  \
    const s16x8* pq = (const s16x8*)(Qu_b + (size_t)r * 64 + g * 8);   \
    const s16x8* pv = (const s16x8*)(Qv_b + (size_t)r * 64 + g * 8);   \
    qu[0] = pq[0]; qu[1] = pq[4];                                      \
    qv[0] = pv[0]; qv[1] = pv[4];                                      \
    int rp = r0 + 1 + l15;                                             \
    if (rp < QL) {                                                     \
      const s16x8* pp = (const s16x8*)(Qv_b + (size_t)rp * 64 + g * 8);\
      qvp[0] = pp[0]; qvp[1] = pp[4];                                  \
    } else { qvp[0] = zv; qvp[1] = zv; }                               \
  }                                                                    \
  int slan[4]; bool crr[4];                                            \
  _Pragma("unroll")                                                    \
  for (int i = 0; i < 4; ++i) {                                        \
    int g4i = g * 4 + i;                                               \
    slan[i] = (lane & 48) | ((l15 + 15 - g4i) & 15);                   \
    crr[i] = (l15 >= g4i + 1);                                         \
  }                                                                    \
  const int sq0 = jq * 4;                                              \
  const int tb0 = sq0 * 64 + 1008 - r0;

// P1: e once; w=exp(e) -> aw fp32 (BFW=false) or wbf bf16 (BFW=true);
// row-sum partials -> lsum. 4096 blocks, 256 threads, no LDS.
template <bool BFW>
__global__ __launch_bounds__(256) void attn_p1(
    const unsigned short* __restrict__ Qu, const unsigned short* __restrict__ Qv,
    const unsigned short* __restrict__ Kp, const unsigned short* __restrict__ Pp,
    const unsigned long long* __restrict__ mbits,
    float* __restrict__ aw, unsigned short* __restrict__ wbf,
    float* __restrict__ lsum, float* __restrict__ Oacc) {
  ATTN_DECODE();

  if (jq == 0) {  // zero the O accumulator region for these rows (16KB/block)
    float4 z4 = {0.f, 0.f, 0.f, 0.f};
    float* dst = Oacc + ((size_t)bh * QL + rblk * 64) * 64 + threadIdx.x * 16;
#pragma unroll
    for (int q = 0; q < 4; ++q) ((float4*)dst)[q] = z4;
  }

  const unsigned short* Qu_b = Qu + (size_t)bh * QL * 64;
  const unsigned short* Qv_b = Qv + (size_t)bh * QL * 64;
  const unsigned short* Kp_b = Kp + (size_t)bh * KT * 64;
  const unsigned short* Pp_b = Pp + (size_t)h * KT * 64;
  const size_t awoff = (size_t)bh * QL * KT;
  const unsigned long long* mb_b = mbits + (size_t)b * QL * 32;

  ATTN_PROLOGUE();

  float l_l[4] = {0.f, 0.f, 0.f, 0.f};

  f32x4 cur[4], nxt[4];
  bd_chunk(cur, Pp_b, qv, qvp, tb0, g, l15);
  s16x8 kb[2][4];
  load_k(kb, Kp_b, sq0 * 64, g, l15);

#pragma unroll
  for (int ss = 0; ss < 4; ++ss) {
    const int s = sq0 + ss;
    const int j0 = s * 64;
    bd_chunk(nxt, Pp_b, qv, qvp, tb0 + (ss + 1) * 64, g, l15);
    f32x4 acc[4];
#pragma unroll
    for (int nf = 0; nf < 4; ++nf) acc[nf] = f32x4{0.f, 0.f, 0.f, 0.f};
    qk_acc(acc, qu, kb);
    if (ss < 3) load_k(kb, Kp_b, (s + 1) * 64, g, l15);
    float bd[4][4];
    bd_gather(bd, cur, nxt[0], slan, crr);
    float e[4][4];
    make_e(e, acc, bd, mb_b, r0, s, g, l15);
#pragma unroll
    for (int nf = 0; nf < 4; ++nf)
#pragma unroll
      for (int i = 0; i < 4; ++i) {
        float p = __expf(e[nf][i]);   // masked -> exactly 0
        size_t idx = awoff + (size_t)(r0 + g * 4 + i) * KT + j0 + nf * 16 + l15;
        if (BFW) wbf[idx] = f2bf(p);
        else     aw[idx] = p;
        l_l[i] += p;
      }
#pragma unroll
    for (int nf = 0; nf < 4; ++nf) cur[nf] = nxt[nf];
  }

  // per-row l partial: 16-lane reduce, lane l15==0 writes rows g*4+i
#pragma unroll
  for (int i = 0; i < 4; ++i) {
    float sL = l_l[i];
#pragma unroll
    for (int d = 1; d < 16; d <<= 1) sL += __shfl_xor(sL, d);
    if (l15 == 0)
      lsum[((size_t)bh * QL + r0 + g * 4 + i) * 8 + jq] = sL;
  }
}

// rl[row] = 1 / sum(lsum[row][0..8))   (32768 rows)
__global__ __launch_bounds__(256) void rsum_kernel(
    const float* __restrict__ lsum, float* __restrict__ rl) {
  int r = blockIdx.x * 256 + threadIdx.x;
  const f32x4* p = (const f32x4*)(lsum + (size_t)r * 8);
  f32x4 a = p[0], c = p[1];
  rl[r] = 1.f / (a[0] + a[1] + a[2] + a[3] + c[0] + c[1] + c[2] + c[3]);
}

// PV pass (fallback, fp32 aw RMW) — byte-identical to R14's validated kernel.
__global__ __launch_bounds__(256) void attn_pv(
    const unsigned short* __restrict__ Vt, const float* __restrict__ rl,
    float* __restrict__ aw, float* __restrict__ Oacc) {
  const int w = threadIdx.x >> 6, lane = threadIdx.x & 63;
  const int g = lane >> 4, l15 = lane & 15;
  const int logical = ((blockIdx.x & 7) << 8) | (blockIdx.x >> 3);  // 2048 blocks
  const int rblk = logical & 15, jq = (logical >> 4) & 3, bh = logical >> 6;
  const int r0 = rblk * 64 + w * 16;

  const unsigned short* Vt_b = Vt + (size_t)bh * 64 * KT;
  float* aw_b = aw + (size_t)bh * QL * KT;
  const float rs = rl[(size_t)bh * QL + r0 + l15];

  f32x4 accO[4];
#pragma unroll
  for (int df = 0; df < 4; ++df) accO[df] = f32x4{0.f, 0.f, 0.f, 0.f};

#pragma unroll 4
  for (int s2 = 0; s2 < 8; ++s2) {
    const int j0 = (jq * 8 + s2) * 64;
    float* ar = aw_b + (size_t)(r0 + l15) * KT + j0 + g * 8;
    f32x4 w0 = *(const f32x4*)(ar);
    f32x4 w1 = *(const f32x4*)(ar + 4);
    f32x4 w2 = *(const f32x4*)(ar + 32);
    f32x4 w3 = *(const f32x4*)(ar + 36);
    w0 *= rs; w1 *= rs; w2 *= rs; w3 *= rs;
    *(f32x4*)(ar) = w0;
    *(f32x4*)(ar + 4) = w1;
    *(f32x4*)(ar + 32) = w2;
    *(f32x4*)(ar + 36) = w3;
    s16x8 pa0 = cvt8(w0, w1);
    s16x8 pa1 = cvt8(w2, w3);
    s16x8 vb[2][4];
    load_v(vb, Vt_b, j0, g, l15);
#pragma unroll
    for (int df = 0; df < 4; ++df) {
      accO[df] = MFMA_BF16(pa0, vb[0][df], accO[df]);
      accO[df] = MFMA_BF16(pa1, vb[1][df], accO[df]);
    }
  }

#pragma unroll
  for (int df = 0; df < 4; ++df)
#pragma unroll
    for (int i = 0; i < 4; ++i)
      atomicAdd(&Oacc[((size_t)bh * QL + r0 + g * 4 + i) * 64 + df * 16 + l15], accO[df][i]);
}

// PV pass (big-ws): read bf16 w scratch, normalize -> fp32 aw (NT store, once),
// fragments = cvt8(normalized) — same math as fallback, different w source.
__global__ __launch_bounds__(256) void attn_pv_bf16(
    const unsigned short* __restrict__ Vt, const float* __restrict__ rl,
    const unsigned short* __restrict__ wbf, float* __restrict__ aw,
    float* __restrict__ Oacc) {
  const int w = threadIdx.x >> 6, lane = threadIdx.x & 63;
  const int g = lane >> 4, l15 = lane & 15;
  const int logical = ((blockIdx.x & 7) << 8) | (blockIdx.x >> 3);  // 2048 blocks
  const int rblk = logical & 15, jq = (logical >> 4) & 3, bh = logical >> 6;
  const int r0 = rblk * 64 + w * 16;

  const unsigned short* Vt_b = Vt + (size_t)bh * 64 * KT;
  const unsigned short* w_b = wbf + (size_t)bh * QL * KT;
  float* aw_b = aw + (size_t)bh * QL * KT;
  const float rs = rl[(size_t)bh * QL + r0 + l15];

  f32x4 accO[4];
#pragma unroll
  for (int df = 0; df < 4; ++df) accO[df] = f32x4{0.f, 0.f, 0.f, 0.f};

#pragma unroll 4
  for (int s2 = 0; s2 < 8; ++s2) {
    const int j0 = (jq * 8 + s2) * 64;
    const unsigned short* wr = w_b + (size_t)(r0 + l15) * KT + j0 + g * 8;
    s16x8 a0 = *(const s16x8*)(wr);        // k = g*8..+8   (kk=0)
    s16x8 a1 = *(const s16x8*)(wr + 32);   // k = 32+g*8..+8 (kk=1)
    f32x4 w0, w1, w2, w3;
#pragma unroll
    for (int t = 0; t < 4; ++t) {
      w0[t] = bf2f((unsigned short)a0[t]) * rs;
      w1[t] = bf2f((unsigned short)a0[t + 4]) * rs;
      w2[t] = bf2f((unsigned short)a1[t]) * rs;
      w3[t] = bf2f((unsigned short)a1[t + 4]) * rs;
    }
    float* ar = aw_b + (size_t)(r0 + l15) * KT + j0 + g * 8;
    __builtin_nontemporal_store(w0, (f32x4*)(ar));
    __builtin_nontemporal_store(w1, (f32x4*)(ar + 4));
    __builtin_nontemporal_store(w2, (f32x4*)(ar + 32));
    __builtin_nontemporal_store(w3, (f32x4*)(ar + 36));
    s16x8 pa0 = cvt8(w0, w1);
    s16x8 pa1 = cvt8(w2, w3);
    s16x8 vb[2][4];
    load_v(vb, Vt_b, j0, g, l15);
#pragma unroll
    for (int df = 0; df < 4; ++df) {
      accO[df] = MFMA_BF16(pa0, vb[0][df], accO[df]);
      accO[df] = MFMA_BF16(pa1, vb[1][df], accO[df]);
    }
  }

#pragma unroll
  for (int df = 0; df < 4; ++df)
#pragma unroll
    for (int i = 0; i < 4; ++i)
      atomicAdd(&Oacc[((size_t)bh * QL + r0 + g * 4 + i) * 64 + df * 16 + l15], accO[df][i]);
}

// C: Oacc [bh][r][64] f32 -> cvb [b][r][h*64+d] bf16
__global__ __launch_bounds__(256) void cast_cv_kernel(
    const float* __restrict__ Oacc, unsigned short* __restrict__ cvb) {
  int t = blockIdx.x * blockDim.x + threadIdx.x;
  int d4 = t & 15, r = (t >> 4) & 1023, bh = t >> 14;
  int b = bh >> 4, h = bh & 15;
  float4 v = ((const float4*)Oacc)[t];
  ushort4 o;
  o.x = f2bf(v.x); o.y = f2bf(v.y); o.z = f2bf(v.z); o.w = f2bf(v.w);
  *(ushort4*)(cvb + (size_t)(b * QL + r) * DM + h * 64 + d4 * 4) = o;
}

// ---------------- launch ----------------

extern "C" void kernel_launch(void* const* d_in, const int* in_sizes, int n_in,
                              void* d_out, int out_size, void* d_ws, size_t ws_size,
                              hipStream_t stream) {
  const float* key_x  = (const float*)d_in[0];
  const float* query  = (const float*)d_in[1];
  const float* memory = (const float*)d_in[2];
  const float* pose   = (const float*)d_in[3];
  const int*   mask   = (const int*)d_in[4];
  const float* u      = (const float*)d_in[5];
  const float* v      = (const float*)d_in[6];
  const float* w_key  = (const float*)d_in[7];
  const float* w_val  = (const float*)d_in[8];
  const float* w_qry  = (const float*)d_in[9];
  const float* w_pos  = (const float*)d_in[10];
  const float* w_out  = (const float*)d_in[11];

  char* ws = (char*)d_ws;
  const size_t MB = 1024 * 1024;
  unsigned short* kv_b  = (unsigned short*)(ws + 0);        // [2][2048][1024] bf16 (8MB)
  unsigned short* q_b   = (unsigned short*)(ws + 8 * MB);   // (4MB)
  unsigned short* pos_b = (unsigned short*)(ws + 12 * MB);  // (4MB)
  unsigned short* wk_t  = (unsigned short*)(ws + 16 * MB);
  unsigned short* wv_t  = (unsigned short*)(ws + 18 * MB);
  unsigned short* wq_t  = (unsigned short*)(ws + 20 * MB);
  unsigned short* wp_t  = (unsigned short*)(ws + 22 * MB);
  unsigned short* wo_t  = (unsigned short*)(ws + 24 * MB);
  unsigned short* Kp    = (unsigned short*)(ws + 26 * MB);  // [2][16][2048][64] (8MB)
  unsigned short* Vt    = (unsigned short*)(ws + 34 * MB);  // [2][16][64][2048] (8MB)
  unsigned short* Qu    = (unsigned short*)(ws + 42 * MB);  // (4MB)
  unsigned short* Qv    = (unsigned short*)(ws + 46 * MB);  // (4MB)
  unsigned short* Pp    = (unsigned short*)(ws + 50 * MB);  // [16][2048][64] (4MB)
  unsigned short* cvb   = (unsigned short*)(ws + 54 * MB);  // (4MB)
  unsigned long long* mb = (unsigned long long*)(ws + 58 * MB);  // (0.5MB)
  // reuse dead regions (after gemm_fused, kv_b/q_b are dead):
  float* Oacc = (float*)(ws + 0);        // [2][16][1024][64] f32 (8MB) over kv_b
  float* lsum = (float*)(ws + 8 * MB);   // [32768][8] f32 (1MB) over q_b
  float* rl   = (float*)(ws + 9 * MB);   // [32768] f32 (128KB) over q_b
  // big-ws path: bf16 w scratch [32][1024][2048] (134.25MB) at ws+60MB
  unsigned short* wbf = (unsigned short*)(ws + 60 * MB);
  const bool big_ws = ws_size >= 196 * MB;

  float* out_cv = (float*)d_out;
  float* out_aw = (float*)d_out + (size_t)BATCH * QL * DM;

  cast_kv_kernel<<<4096, 256, 0, stream>>>(memory, key_x, kv_b);
  cast4_kernel<<<2048, 256, 0, stream>>>(query, q_b, BATCH * QL * DM / 4);
  cast4_kernel<<<2048, 256, 0, stream>>>(pose, pos_b, KT * DM / 4);
  transpose_cast_kernel<<<dim3(32, 32, 5), dim3(32, 8), 0, stream>>>(
      w_key, w_val, w_qry, w_pos, w_out, wk_t, wv_t, wq_t, wp_t, wo_t);
  pack_mask_kernel<<<16384, 256, 0, stream>>>(mask, mb);

  gemm_fused_kernel<<<768, 256, 0, stream>>>(kv_b, q_b, pos_b, wk_t, wv_t, wq_t, wp_t,
                                             Kp, Vt, Qu, Qv, Pp, u, v);

  if (big_ws) {
    attn_p1<true><<<4096, 256, 0, stream>>>(Qu, Qv, Kp, Pp, mb, out_aw, wbf, lsum, Oacc);
    rsum_kernel<<<128, 256, 0, stream>>>(lsum, rl);
    attn_pv_bf16<<<2048, 256, 0, stream>>>(Vt, rl, wbf, out_aw, Oacc);
  } else {
    attn_p1<false><<<4096, 256, 0, stream>>>(Qu, Qv, Kp, Pp, mb, out_aw, wbf, lsum, Oacc);
    rsum_kernel<<<128, 256, 0, stream>>>(lsum, rl);
    attn_pv<<<2048, 256, 0, stream>>>(Vt, rl, out_aw, Oacc);
  }
  cast_cv_kernel<<<2048, 256, 0, stream>>>(Oacc, cvb);

  gemm_out_kernel<<<dim3(8, 16), 256, 0, stream>>>(cvb, wo_t, out_cv);
}